// Round 3
// baseline (1203.899 us; speedup 1.0000x reference)
//
#include <hip/hip_runtime.h>

// EGNN E_GCL fused kernels for MI355X (gfx950), bf16 MFMA path.
// Round 3: (1) DPP-based segmented suffix scan (replaces 576 ds_bpermute/tile
// with VALU ops), (2) XOR bank swizzle on LDS fragment tiles (8-way -> 2-way
// write conflicts), (3) pre-sorted (row,col) int2 pairs (shorter gather chain),
// (4) register diet: Wc1 fragments reloaded per tile, __launch_bounds__(256,3).

typedef float f32x4 __attribute__((ext_vector_type(4)));
typedef short s16x8 __attribute__((ext_vector_type(8)));

#define NN   50000
#define EE   1600000
#define NHF  6400000   // N*128
#define NBIN 50000

__device__ __forceinline__ unsigned short f2bf(float x){
  union { float f; unsigned int u; } v; v.f = x;
  unsigned int r = v.u + 0x7fffu + ((v.u >> 16) & 1u);
  return (unsigned short)(r >> 16);
}
__device__ __forceinline__ unsigned int pack2(float a, float b){
  return (unsigned int)f2bf(a) | ((unsigned int)f2bf(b) << 16);
}
__device__ __forceinline__ float silu_f(float x){ return x / (1.f + __expf(-x)); }

__device__ __forceinline__ f32x4 mfma16(s16x8 a, s16x8 b, f32x4 c){
  return __builtin_amdgcn_mfma_f32_16x16x32_bf16(a, b, c, 0, 0, 0);
}

// DPP helpers: row_shl:N (0x100+N) -> lane i reads lane i+N within its 16-lane
// row (suffix direction); row_shr:1 (0x111) -> lane i reads lane i-1.
template<int CTRL> __device__ __forceinline__ float dppf(float x){
  return __int_as_float(__builtin_amdgcn_update_dpp(0, __float_as_int(x), CTRL, 0xF, 0xF, true));
}
template<int CTRL> __device__ __forceinline__ int dppi(int x){
  return __builtin_amdgcn_update_dpp(-1, x, CTRL, 0xF, 0xF, false);
}

// Swizzled LDS fragment address: frag fi, slot (0..63), 16B per slot.
// byte = fi*1024 + ((slot*16) ^ ((fi&3)*32))  -> spreads the 4 frags written
// simultaneously by the gather across distinct bank groups.
__device__ __forceinline__ short* sptr(short* base, int fi, int slot){
  return (short*)((char*)base + (fi << 10) + (((slot << 4) ^ ((fi & 3) << 5))));
}

// ---------- weight pack: A-fragments of W^T ----------
__global__ void pack_weights(const float* __restrict__ We1, const float* __restrict__ We2,
                             const float* __restrict__ Wc1, const float* __restrict__ Wn1,
                             const float* __restrict__ Wn2, short* __restrict__ wp)
{
  int b = blockIdx.x;              // 7*32 blocks, 64 threads
  int m = b >> 5, t = b & 31;
  int ft = t >> 2, ks = t & 3;
  int lane = threadIdx.x;
  const float* src;
  switch (m) {
    case 0: src = We1;            break;
    case 1: src = We1 + 128*128;  break;
    case 2: src = We2;            break;
    case 3: src = Wc1;            break;
    case 4: src = Wn1;            break;
    case 5: src = Wn1 + 128*128;  break;
    default: src = Wn2;           break;
  }
  short* dst = wp + m*16384 + (((ft<<2) + ks)*64 + lane)*8;
  int f  = (ft<<4) + (lane & 15);
  int kb = (ks<<5) + ((lane >> 4) << 3);
#pragma unroll
  for (int j = 0; j < 8; ++j)
    dst[j] = (short)f2bf(src[(kb + j)*128 + f]);
}

// ---------- h -> bf16 ----------
__global__ void hconv(const float* __restrict__ h, short* __restrict__ hb)
{
  int i = (blockIdx.x*256 + threadIdx.x) * 8;
  f32x4 a = *(const f32x4*)(h + i);
  f32x4 b = *(const f32x4*)(h + i + 4);
  s16x8 o;
  o[0]=(short)f2bf(a.x); o[1]=(short)f2bf(a.y); o[2]=(short)f2bf(a.z); o[3]=(short)f2bf(a.w);
  o[4]=(short)f2bf(b.x); o[5]=(short)f2bf(b.y); o[6]=(short)f2bf(b.z); o[7]=(short)f2bf(b.w);
  *(s16x8*)(hb + i) = o;
}

// ---------- counting sort by row: hist -> scan -> scatter (row,col) ----------
__global__ void hist_k(const int* __restrict__ eidx, int* __restrict__ hist)
{
  int e = blockIdx.x*256 + threadIdx.x;
  if (e < EE) atomicAdd(&hist[eidx[e]], 1);
}

__global__ void scan_k(const int* __restrict__ hist, int* __restrict__ cur)
{
  __shared__ int s_a[256];
  const int t = threadIdx.x;
  const int lo = t * 196;
  const int hi = (lo + 196 < NBIN) ? lo + 196 : NBIN;
  int s = 0;
  for (int i = lo; i < hi; ++i) s += hist[i];
  s_a[t] = s;
  __syncthreads();
  int acc = s;
#pragma unroll
  for (int d = 1; d < 256; d <<= 1) {
    int u = (t >= d) ? s_a[t - d] : 0;
    __syncthreads();
    acc += u;
    s_a[t] = acc;
    __syncthreads();
  }
  int run = acc - s;
  for (int i = lo; i < hi; ++i) { cur[i] = run; run += hist[i]; }
}

__global__ void scatter_k(const int* __restrict__ eidx, int* __restrict__ cur,
                          int2* __restrict__ rc)
{
  int e = blockIdx.x*256 + threadIdx.x;
  if (e < EE) {
    int r = eidx[e], c = eidx[EE + e];
    int p = atomicAdd(&cur[r], 1);
    int2 v; v.x = r; v.y = c;
    rc[p] = v;
  }
}

// ---------- edge kernel ----------
__global__ __launch_bounds__(256, 3)
void edge_kernel(const short* __restrict__ hb, const float* __restrict__ coord,
                 const int2* __restrict__ rc, const short* __restrict__ wp,
                 const float* __restrict__ be1, const float* __restrict__ be2,
                 const float* __restrict__ bc1, const float* __restrict__ We1,
                 const float* __restrict__ Wc2,
                 float* __restrict__ aggh, float* __restrict__ aggc,
                 float* __restrict__ cntb)
{
  __shared__ short sAf[2][16*64*8];      // 32 KiB, swizzled frag tiles
  __shared__ float s_vec[5][128];        // be1, be2, bc1, W1c, Wc2
  __shared__ float s_rad[64];
  __shared__ float s_cd[64][3];
  __shared__ int   s_ri[64];
  __shared__ float s_phi[64];

  const int tid  = threadIdx.x;
  const int w    = tid >> 6, lane = tid & 63;
  const int ecol = lane & 15, rgrp = lane >> 4;

  if (tid < 128) {
    s_vec[0][tid] = be1[tid];
    s_vec[1][tid] = be2[tid];
    s_vec[2][tid] = bc1[tid];
    s_vec[3][tid] = We1[256*128 + tid];
    s_vec[4][tid] = Wc2[tid];
  }

  // persistent weight fragments: We1a, We1b (w1) + We2 (w2) = 96 VGPRs.
  // Wc1 is reloaded per tile (L2-resident) to cut register pressure.
  s16x8 w1[2][2][4], w2[2][4];
#pragma unroll
  for (int m = 0; m < 2; ++m)
#pragma unroll
    for (int f2 = 0; f2 < 2; ++f2)
#pragma unroll
      for (int ks = 0; ks < 4; ++ks)
        w1[m][f2][ks] = *(const s16x8*)(wp + m*16384 + ((((2*w+f2)<<2) + ks)*64 + lane)*8);
#pragma unroll
  for (int f2 = 0; f2 < 2; ++f2)
#pragma unroll
    for (int ks = 0; ks < 4; ++ks)
      w2[f2][ks] = *(const s16x8*)(wp + 2*16384 + ((((2*w+f2)<<2) + ks)*64 + lane)*8);

  short* sb0 = &sAf[0][0];
  short* sb1 = &sAf[1][0];

  const int el = tid >> 2, q = tid & 3;       // gather role: 4 threads per edge
  const int fi0 = ((el >> 4) << 2) + q, er = el & 15;

  for (int t = blockIdx.x; t < (EE/64); t += gridDim.x) {
    const int e0 = t << 6;
    if (tid < 64) {
      int2 v = rc[e0 + tid];
      int r = v.x, c = v.y;
      s_ri[tid] = r;
      float ax = coord[3*r], ay = coord[3*r+1], az = coord[3*r+2];
      float bx = coord[3*c], by = coord[3*c+1], bz = coord[3*c+2];
      float dx = ax-bx, dy = ay-by, dz = az-bz;
      s_cd[tid][0] = dx; s_cd[tid][1] = dy; s_cd[tid][2] = dz;
      s_rad[tid] = dx*dx + dy*dy + dz*dz;
      s_phi[tid] = 0.f;
    }
    { // gather h rows (bf16) into swizzled fragment order
      int2 v = rc[e0 + el];
      const s16x8* hr = (const s16x8*)(hb + (size_t)v.x*128 + q*32);
      const s16x8* hc = (const s16x8*)(hb + (size_t)v.y*128 + q*32);
#pragma unroll
      for (int lg = 0; lg < 4; ++lg) {
        *(s16x8*)sptr(sb0, fi0, lg*16 + er) = hr[lg];
        *(s16x8*)sptr(sb1, fi0, lg*16 + er) = hc[lg];
      }
    }
    __syncthreads();                                            // S1

    // GEMM1: D[f][e] = W1a^T hrow^T + W1b^T hcol^T
    f32x4 acc[2][4] = {};
#pragma unroll
    for (int et = 0; et < 4; ++et)
#pragma unroll
      for (int ks = 0; ks < 4; ++ks) {
        s16x8 br = *(const s16x8*)sptr(sb0, et*4+ks, lane);
        s16x8 bc = *(const s16x8*)sptr(sb1, et*4+ks, lane);
        acc[0][et] = mfma16(w1[0][0][ks], br, acc[0][et]);
        acc[1][et] = mfma16(w1[0][1][ks], br, acc[1][et]);
        acc[0][et] = mfma16(w1[1][0][ks], bc, acc[0][et]);
        acc[1][et] = mfma16(w1[1][1][ks], bc, acc[1][et]);
      }
    __syncthreads();                                            // S2

    // epilogue1: + radial*W1c + be1, SiLU -> t1 frags into sb0
#pragma unroll
    for (int f2 = 0; f2 < 2; ++f2) {
      const int ft = 2*w + f2, f0 = ft*16 + rgrp*4;
      const int ks2 = f0 >> 5, lg2 = (f0 & 31) >> 3, j0 = f0 & 7;
      f32x4 w1c = *(const f32x4*)&s_vec[3][f0];
      f32x4 b1  = *(const f32x4*)&s_vec[0][f0];
#pragma unroll
      for (int et = 0; et < 4; ++et) {
        float rad = s_rad[et*16 + ecol];
        f32x4 x = acc[f2][et];
        x.x = silu_f(x.x + rad*w1c.x + b1.x);
        x.y = silu_f(x.y + rad*w1c.y + b1.y);
        x.z = silu_f(x.z + rad*w1c.z + b1.z);
        x.w = silu_f(x.w + rad*w1c.w + b1.w);
        uint2 p; p.x = pack2(x.x, x.y); p.y = pack2(x.z, x.w);
        *(uint2*)((char*)sptr(sb0, et*4 + ks2, lg2*16 + ecol) + 2*j0) = p;
      }
    }
    __syncthreads();                                            // S3

    // GEMM2: edge_feat
    f32x4 a2[2][4] = {};
#pragma unroll
    for (int et = 0; et < 4; ++et)
#pragma unroll
      for (int ks = 0; ks < 4; ++ks) {
        s16x8 b = *(const s16x8*)sptr(sb0, et*4+ks, lane);
        a2[0][et] = mfma16(w2[0][ks], b, a2[0][et]);
        a2[1][et] = mfma16(w2[1][ks], b, a2[1][et]);
      }
    // epilogue2: + be2, SiLU; frags into sb1; DPP segmented suffix-sum over
    // the 16-lane edge group (rows sorted => segments contiguous), heads
    // issue the deduplicated global atomics.
#pragma unroll
    for (int et = 0; et < 4; ++et) {
      const int r_l = s_ri[et*16 + ecol];
      f32x4 xx0, xx1;
#pragma unroll
      for (int f2 = 0; f2 < 2; ++f2) {
        const int ft = 2*w + f2, f0 = ft*16 + rgrp*4;
        const int ks2 = f0 >> 5, lg2 = (f0 & 31) >> 3, j0 = f0 & 7;
        f32x4 b2 = *(const f32x4*)&s_vec[1][f0];
        f32x4 x = a2[f2][et];
        x.x = silu_f(x.x + b2.x); x.y = silu_f(x.y + b2.y);
        x.z = silu_f(x.z + b2.z); x.w = silu_f(x.w + b2.w);
        uint2 p; p.x = pack2(x.x, x.y); p.y = pack2(x.z, x.w);
        *(uint2*)((char*)sptr(sb1, et*4 + ks2, lg2*16 + ecol) + 2*j0) = p;
        if (f2 == 0) xx0 = x; else xx1 = x;
      }
#define SEG_ROUND(CTRL) { \
      int rn = dppi<CTRL>(r_l); \
      bool ok = (rn == r_l); \
      float u; \
      u = dppf<CTRL>(xx0.x); xx0.x += ok ? u : 0.f; \
      u = dppf<CTRL>(xx0.y); xx0.y += ok ? u : 0.f; \
      u = dppf<CTRL>(xx0.z); xx0.z += ok ? u : 0.f; \
      u = dppf<CTRL>(xx0.w); xx0.w += ok ? u : 0.f; \
      u = dppf<CTRL>(xx1.x); xx1.x += ok ? u : 0.f; \
      u = dppf<CTRL>(xx1.y); xx1.y += ok ? u : 0.f; \
      u = dppf<CTRL>(xx1.z); xx1.z += ok ? u : 0.f; \
      u = dppf<CTRL>(xx1.w); xx1.w += ok ? u : 0.f; }
      SEG_ROUND(0x101)   // row_shl:1
      SEG_ROUND(0x102)   // row_shl:2
      SEG_ROUND(0x104)   // row_shl:4
      SEG_ROUND(0x108)   // row_shl:8
#undef SEG_ROUND
      // head detection: previous lane's row via row_shr:1 (OOB -> -1)
      const int rprev = dppi<0x111>(r_l);
      if (rprev != r_l) {
        const int f0a = (2*w+0)*16 + rgrp*4;
        const int f0b = (2*w+1)*16 + rgrp*4;
        float* aga = aggh + (size_t)r_l*128 + f0a;
        float* agb = aggh + (size_t)r_l*128 + f0b;
        atomicAdd(aga+0, xx0.x); atomicAdd(aga+1, xx0.y);
        atomicAdd(aga+2, xx0.z); atomicAdd(aga+3, xx0.w);
        atomicAdd(agb+0, xx1.x); atomicAdd(agb+1, xx1.y);
        atomicAdd(agb+2, xx1.z); atomicAdd(agb+3, xx1.w);
      }
    }
    __syncthreads();                                            // S4

    // GEMM3 (f2-split, Wc1 frags reloaded per pass to cap register pressure)
    float pacc[4] = {0.f, 0.f, 0.f, 0.f};
#pragma unroll
    for (int f2 = 0; f2 < 2; ++f2) {
      const short* p3 = wp + 3*16384;
      asm volatile("" : "+s"(p3));     // defeat LICM: keep loads inside tile loop
      s16x8 wf3[4];
#pragma unroll
      for (int ks = 0; ks < 4; ++ks)
        wf3[ks] = *(const s16x8*)(p3 + ((((2*w+f2)<<2) + ks)*64 + lane)*8);
      f32x4 a3[4] = {};
#pragma unroll
      for (int et = 0; et < 4; ++et)
#pragma unroll
        for (int ks = 0; ks < 4; ++ks) {
          s16x8 b = *(const s16x8*)sptr(sb1, et*4+ks, lane);
          a3[et] = mfma16(wf3[ks], b, a3[et]);
        }
      const int f0 = (2*w+f2)*16 + rgrp*4;
      f32x4 bc = *(const f32x4*)&s_vec[2][f0];
      f32x4 wc = *(const f32x4*)&s_vec[4][f0];
#pragma unroll
      for (int et = 0; et < 4; ++et) {
        f32x4 x = a3[et];
        pacc[et] += silu_f(x.x + bc.x)*wc.x + silu_f(x.y + bc.y)*wc.y
                  + silu_f(x.z + bc.z)*wc.z + silu_f(x.w + bc.w)*wc.w;
      }
    }
#pragma unroll
    for (int et = 0; et < 4; ++et) {
      float p = pacc[et];
      p += __shfl_xor(p, 16);
      p += __shfl_xor(p, 32);
      if (rgrp == 0) atomicAdd(&s_phi[et*16 + ecol], p);
    }
    __syncthreads();                                            // S5

    // coord aggregation: segmented suffix-sum over the 64 sorted rows
    if (tid < 64) {
      int r = s_ri[tid];
      float ph = s_phi[tid];
      float cx = s_cd[tid][0]*ph, cy = s_cd[tid][1]*ph, cz = s_cd[tid][2]*ph, c1 = 1.f;
#pragma unroll
      for (int d = 1; d < 64; d <<= 1) {
        const int sl = tid + d;
        int   r2 = __shfl(r,  sl, 64);
        float ux = __shfl(cx, sl, 64), uy = __shfl(cy, sl, 64);
        float uz = __shfl(cz, sl, 64), uw = __shfl(c1, sl, 64);
        if ((sl < 64) && (r2 == r)) { cx+=ux; cy+=uy; cz+=uz; c1+=uw; }
      }
      if (tid == 0 || s_ri[tid-1] != r) {
        atomicAdd(&aggc[3*r+0], cx); atomicAdd(&aggc[3*r+1], cy);
        atomicAdd(&aggc[3*r+2], cz); atomicAdd(&cntb[r], c1);
      }
    }
    __syncthreads();                                            // S6
  }
}

// ---------- node kernel ----------
__global__ __launch_bounds__(256, 2)
void node_kernel(const short* __restrict__ hb, const float* __restrict__ h32,
                 const short* __restrict__ wp, const float* __restrict__ bn1,
                 const float* __restrict__ bn2, float* __restrict__ hout)
{
  __shared__ short sA[2][16][64][8];
  __shared__ float s_vec[2][128];
  __shared__ float s_out[64][132];
  const int tid  = threadIdx.x, w = tid >> 6, lane = tid & 63;
  const int ecol = lane & 15, rgrp = lane >> 4;
  if (tid < 128) { s_vec[0][tid] = bn1[tid]; s_vec[1][tid] = bn2[tid]; }

  s16x8 wf[3][2][4];
#pragma unroll
  for (int m = 0; m < 3; ++m)
#pragma unroll
    for (int f2 = 0; f2 < 2; ++f2)
#pragma unroll
      for (int ks = 0; ks < 4; ++ks)
        wf[m][f2][ks] = *(const s16x8*)(wp + (4+m)*16384 + ((((2*w+f2)<<2) + ks)*64 + lane)*8);

  const int n0 = blockIdx.x << 6;
  const int el = tid >> 2, q = tid & 3;
  const int fi0 = ((el >> 4) << 2) + q, er = el & 15;
  {
    const int node = n0 + el;
    if (node < NN) {
      const s16x8* hr = (const s16x8*)(hb + node*128 + q*32);
      const float* ap = hout + node*128 + q*32;   // agg_h lives in d_out
#pragma unroll
      for (int lg = 0; lg < 4; ++lg) {
        *(s16x8*)&sA[0][fi0][lg*16 + er][0] = hr[lg];
        f32x4 u = *(const f32x4*)(ap + lg*8);
        f32x4 v = *(const f32x4*)(ap + lg*8 + 4);
        s16x8 o;
        o[0]=(short)f2bf(u.x); o[1]=(short)f2bf(u.y); o[2]=(short)f2bf(u.z); o[3]=(short)f2bf(u.w);
        o[4]=(short)f2bf(v.x); o[5]=(short)f2bf(v.y); o[6]=(short)f2bf(v.z); o[7]=(short)f2bf(v.w);
        *(s16x8*)&sA[1][fi0][lg*16 + er][0] = o;
      }
    } else {
      s16x8 z = {};
#pragma unroll
      for (int lg = 0; lg < 4; ++lg) {
        *(s16x8*)&sA[0][fi0][lg*16 + er][0] = z;
        *(s16x8*)&sA[1][fi0][lg*16 + er][0] = z;
      }
    }
  }
  __syncthreads();

  f32x4 acc[2][4] = {};
#pragma unroll
  for (int et = 0; et < 4; ++et)
#pragma unroll
    for (int ks = 0; ks < 4; ++ks) {
      s16x8 bh = *(const s16x8*)&sA[0][et*4+ks][lane][0];
      s16x8 ba = *(const s16x8*)&sA[1][et*4+ks][lane][0];
      acc[0][et] = mfma16(wf[0][0][ks], bh, acc[0][et]);
      acc[1][et] = mfma16(wf[0][1][ks], bh, acc[1][et]);
      acc[0][et] = mfma16(wf[1][0][ks], ba, acc[0][et]);
      acc[1][et] = mfma16(wf[1][1][ks], ba, acc[1][et]);
    }
  __syncthreads();
#pragma unroll
  for (int f2 = 0; f2 < 2; ++f2) {
    const int ft = 2*w + f2, f0 = ft*16 + rgrp*4;
    const int ks2 = f0 >> 5, lg2 = (f0 & 31) >> 3, j0 = f0 & 7;
    f32x4 b1 = *(const f32x4*)&s_vec[0][f0];
#pragma unroll
    for (int et = 0; et < 4; ++et) {
      f32x4 x = acc[f2][et];
      x.x = silu_f(x.x + b1.x); x.y = silu_f(x.y + b1.y);
      x.z = silu_f(x.z + b1.z); x.w = silu_f(x.w + b1.w);
      uint2 p; p.x = pack2(x.x, x.y); p.y = pack2(x.z, x.w);
      *(uint2*)&sA[0][et*4 + ks2][lg2*16 + ecol][j0] = p;
    }
  }
  __syncthreads();

  f32x4 a2[2][4] = {};
#pragma unroll
  for (int et = 0; et < 4; ++et)
#pragma unroll
    for (int ks = 0; ks < 4; ++ks) {
      s16x8 b = *(const s16x8*)&sA[0][et*4+ks][lane][0];
      a2[0][et] = mfma16(wf[2][0][ks], b, a2[0][et]);
      a2[1][et] = mfma16(wf[2][1][ks], b, a2[1][et]);
    }
#pragma unroll
  for (int f2 = 0; f2 < 2; ++f2) {
    const int f0 = (2*w+f2)*16 + rgrp*4;
    f32x4 b2 = *(const f32x4*)&s_vec[1][f0];
#pragma unroll
    for (int et = 0; et < 4; ++et) {
      f32x4 x = a2[f2][et];
      x.x += b2.x; x.y += b2.y; x.z += b2.z; x.w += b2.w;
      *(f32x4*)&s_out[et*16 + ecol][f0] = x;
    }
  }
  __syncthreads();
  {
    const int node = n0 + el;
    if (node < NN) {
#pragma unroll
      for (int i = 0; i < 8; ++i) {
        f32x4 o  = *(const f32x4*)&s_out[el][q*32 + i*4];
        f32x4 hv = *(const f32x4*)(h32 + node*128 + q*32 + i*4);
        o.x += hv.x; o.y += hv.y; o.z += hv.z; o.w += hv.w;
        *(f32x4*)(hout + node*128 + q*32 + i*4) = o;
      }
    }
  }
}

// ---------- coord kernel ----------
__global__ void coord_kernel(const float* __restrict__ coord, const float* __restrict__ aggc,
                             const float* __restrict__ cntb, float* __restrict__ out)
{
  int i = blockIdx.x*256 + threadIdx.x;
  if (i < NN) {
    float inv = 1.f / fmaxf(cntb[i], 1.f);
    out[NHF + 3*i+0] = coord[3*i+0] + aggc[3*i+0]*inv;
    out[NHF + 3*i+1] = coord[3*i+1] + aggc[3*i+1]*inv;
    out[NHF + 3*i+2] = coord[3*i+2] + aggc[3*i+2]*inv;
  }
}

extern "C" void kernel_launch(void* const* d_in, const int* in_sizes, int n_in,
                              void* d_out, int out_size, void* d_ws, size_t ws_size,
                              hipStream_t stream)
{
  (void)in_sizes; (void)n_in; (void)out_size; (void)ws_size;
  const float* h    = (const float*)d_in[0];
  const float* crd  = (const float*)d_in[1];
  const int*   eidx = (const int*)  d_in[2];
  const float* We1  = (const float*)d_in[3];
  const float* be1  = (const float*)d_in[4];
  const float* We2  = (const float*)d_in[5];
  const float* be2  = (const float*)d_in[6];
  const float* Wn1  = (const float*)d_in[7];
  const float* bn1  = (const float*)d_in[8];
  const float* Wn2  = (const float*)d_in[9];
  const float* bn2  = (const float*)d_in[10];
  const float* Wc1  = (const float*)d_in[11];
  const float* bc1  = (const float*)d_in[12];
  const float* Wc2  = (const float*)d_in[13];
  float* out = (float*)d_out;
  char*  ws  = (char*)d_ws;

  short* hb   = (short*)ws;                    // 12,800,000 B
  short* wp   = (short*)(ws + 12800000);       //    229,376 B
  float* aggc = (float*)(ws + 13029376);       //    600,000 B
  float* cntb = (float*)(ws + 13629376);       //    200,000 B
  int*   hist = (int*)  (ws + 13829376);       //    200,000 B
  int*   cur  = (int*)  (ws + 14029376);       //    200,000 B
  int2*  rc   = (int2*) (ws + 14229376);       // 12,800,000 B  (end: 27,029,376)

  // zero accumulators every call (harness does not re-poison between replays)
  hipMemsetAsync(out, 0, (size_t)NHF*4, stream);          // agg_h region of d_out
  hipMemsetAsync(ws + 13029376, 0, 800000, stream);       // agg_c + cnt
  hipMemsetAsync(ws + 13829376, 0, 200000, stream);       // hist

  pack_weights<<<dim3(224), dim3(64), 0, stream>>>(We1, We2, Wc1, Wn1, Wn2, wp);
  hconv<<<dim3(3125), dim3(256), 0, stream>>>(h, hb);
  hist_k<<<dim3(6250), dim3(256), 0, stream>>>(eidx, hist);
  scan_k<<<dim3(1), dim3(256), 0, stream>>>(hist, cur);
  scatter_k<<<dim3(6250), dim3(256), 0, stream>>>(eidx, cur, rc);
  edge_kernel<<<dim3(2048), dim3(256), 0, stream>>>(hb, crd, rc, wp,
                                                    be1, be2, bc1, We1, Wc2,
                                                    out, aggc, cntb);
  node_kernel<<<dim3(782), dim3(256), 0, stream>>>(hb, h, wp, bn1, bn2, out);
  coord_kernel<<<dim3(196), dim3(256), 0, stream>>>(crd, aggc, cntb, out);
}

// Round 4
// 834.504 us; speedup vs baseline: 1.4427x; 1.4427x over previous
//
#include <hip/hip_runtime.h>

// EGNN E_GCL fused kernels for MI355X (gfx950), bf16 MFMA path.
// Round 4: revert R3's Wc1 per-tile reload (L2-stall regression: 754->927us);
// keep DPP segmented scan + LDS XOR swizzle + sorted (row,col) pairs.
// New: (a) silu via v_rcp_f32 approx instead of IEEE division sequence
// (~10 VALU -> ~5 per silu), (b) v_cvt_pk_bf16_f32 for all f32->bf16 packing
// (~10 VALU -> 1 per pair). R2 evidence: VALUBusy 52% dominant pipe.

typedef float f32x4 __attribute__((ext_vector_type(4)));
typedef short s16x8 __attribute__((ext_vector_type(8)));

#define NN   50000
#define EE   1600000
#define NHF  6400000   // N*128
#define NBIN 50000

__device__ __forceinline__ unsigned short f2bf(float x){
  union { float f; unsigned int u; } v; v.f = x;
  unsigned int r = v.u + 0x7fffu + ((v.u >> 16) & 1u);
  return (unsigned short)(r >> 16);
}
// packed f32x2 -> bf16x2 in one instruction (lo = a, hi = b)
__device__ __forceinline__ unsigned int pack2(float a, float b){
  unsigned int r;
  asm("v_cvt_pk_bf16_f32 %0, %1, %2" : "=v"(r) : "v"(a), "v"(b));
  return r;
}
// silu with hardware-approx reciprocal (1 trans op instead of IEEE div chain)
__device__ __forceinline__ float silu_f(float x){
  return x * __builtin_amdgcn_rcpf(1.f + __expf(-x));
}

__device__ __forceinline__ f32x4 mfma16(s16x8 a, s16x8 b, f32x4 c){
  return __builtin_amdgcn_mfma_f32_16x16x32_bf16(a, b, c, 0, 0, 0);
}

// DPP helpers: row_shl:N (0x100+N) -> lane i reads lane i+N within its 16-lane
// row (suffix direction); row_shr:1 (0x111) -> lane i reads lane i-1.
template<int CTRL> __device__ __forceinline__ float dppf(float x){
  return __int_as_float(__builtin_amdgcn_update_dpp(0, __float_as_int(x), CTRL, 0xF, 0xF, true));
}
template<int CTRL> __device__ __forceinline__ int dppi(int x){
  return __builtin_amdgcn_update_dpp(-1, x, CTRL, 0xF, 0xF, false);
}

// Swizzled LDS fragment address: frag fi, slot (0..63), 16B per slot.
__device__ __forceinline__ short* sptr(short* base, int fi, int slot){
  return (short*)((char*)base + (fi << 10) + (((slot << 4) ^ ((fi & 3) << 5))));
}

// ---------- weight pack: A-fragments of W^T ----------
__global__ void pack_weights(const float* __restrict__ We1, const float* __restrict__ We2,
                             const float* __restrict__ Wc1, const float* __restrict__ Wn1,
                             const float* __restrict__ Wn2, short* __restrict__ wp)
{
  int b = blockIdx.x;              // 7*32 blocks, 64 threads
  int m = b >> 5, t = b & 31;
  int ft = t >> 2, ks = t & 3;
  int lane = threadIdx.x;
  const float* src;
  switch (m) {
    case 0: src = We1;            break;
    case 1: src = We1 + 128*128;  break;
    case 2: src = We2;            break;
    case 3: src = Wc1;            break;
    case 4: src = Wn1;            break;
    case 5: src = Wn1 + 128*128;  break;
    default: src = Wn2;           break;
  }
  short* dst = wp + m*16384 + (((ft<<2) + ks)*64 + lane)*8;
  int f  = (ft<<4) + (lane & 15);
  int kb = (ks<<5) + ((lane >> 4) << 3);
#pragma unroll
  for (int j = 0; j < 8; ++j)
    dst[j] = (short)f2bf(src[(kb + j)*128 + f]);
}

// ---------- h -> bf16 ----------
__global__ void hconv(const float* __restrict__ h, short* __restrict__ hb)
{
  int i = (blockIdx.x*256 + threadIdx.x) * 8;
  f32x4 a = *(const f32x4*)(h + i);
  f32x4 b = *(const f32x4*)(h + i + 4);
  uint4 o;
  o.x = pack2(a.x, a.y); o.y = pack2(a.z, a.w);
  o.z = pack2(b.x, b.y); o.w = pack2(b.z, b.w);
  *(uint4*)(hb + i) = o;
}

// ---------- counting sort by row: hist -> scan -> scatter (row,col) ----------
__global__ void hist_k(const int* __restrict__ eidx, int* __restrict__ hist)
{
  int e = blockIdx.x*256 + threadIdx.x;
  if (e < EE) atomicAdd(&hist[eidx[e]], 1);
}

__global__ void scan_k(const int* __restrict__ hist, int* __restrict__ cur)
{
  __shared__ int s_a[256];
  const int t = threadIdx.x;
  const int lo = t * 196;
  const int hi = (lo + 196 < NBIN) ? lo + 196 : NBIN;
  int s = 0;
  for (int i = lo; i < hi; ++i) s += hist[i];
  s_a[t] = s;
  __syncthreads();
  int acc = s;
#pragma unroll
  for (int d = 1; d < 256; d <<= 1) {
    int u = (t >= d) ? s_a[t - d] : 0;
    __syncthreads();
    acc += u;
    s_a[t] = acc;
    __syncthreads();
  }
  int run = acc - s;
  for (int i = lo; i < hi; ++i) { cur[i] = run; run += hist[i]; }
}

__global__ void scatter_k(const int* __restrict__ eidx, int* __restrict__ cur,
                          int2* __restrict__ rc)
{
  int e = blockIdx.x*256 + threadIdx.x;
  if (e < EE) {
    int r = eidx[e], c = eidx[EE + e];
    int p = atomicAdd(&cur[r], 1);
    int2 v; v.x = r; v.y = c;
    rc[p] = v;
  }
}

// ---------- edge kernel ----------
__global__ __launch_bounds__(256, 2)
void edge_kernel(const short* __restrict__ hb, const float* __restrict__ coord,
                 const int2* __restrict__ rc, const short* __restrict__ wp,
                 const float* __restrict__ be1, const float* __restrict__ be2,
                 const float* __restrict__ bc1, const float* __restrict__ We1,
                 const float* __restrict__ Wc2,
                 float* __restrict__ aggh, float* __restrict__ aggc,
                 float* __restrict__ cntb)
{
  __shared__ short sAf[2][16*64*8];      // 32 KiB, swizzled frag tiles
  __shared__ float s_vec[5][128];        // be1, be2, bc1, W1c, Wc2
  __shared__ float s_rad[64];
  __shared__ float s_cd[64][3];
  __shared__ int   s_ri[64];
  __shared__ float s_phi[64];

  const int tid  = threadIdx.x;
  const int w    = tid >> 6, lane = tid & 63;
  const int ecol = lane & 15, rgrp = lane >> 4;

  if (tid < 128) {
    s_vec[0][tid] = be1[tid];
    s_vec[1][tid] = be2[tid];
    s_vec[2][tid] = bc1[tid];
    s_vec[3][tid] = We1[256*128 + tid];
    s_vec[4][tid] = Wc2[tid];
  }

  // persistent weight fragments: We1a, We1b, We2, Wc1 = 128 VGPRs
  s16x8 wf[4][2][4];
#pragma unroll
  for (int m = 0; m < 4; ++m)
#pragma unroll
    for (int f2 = 0; f2 < 2; ++f2)
#pragma unroll
      for (int ks = 0; ks < 4; ++ks)
        wf[m][f2][ks] = *(const s16x8*)(wp + m*16384 + ((((2*w+f2)<<2) + ks)*64 + lane)*8);

  short* sb0 = &sAf[0][0];
  short* sb1 = &sAf[1][0];

  const int el = tid >> 2, q = tid & 3;       // gather role: 4 threads per edge
  const int fi0 = ((el >> 4) << 2) + q, er = el & 15;

  for (int t = blockIdx.x; t < (EE/64); t += gridDim.x) {
    const int e0 = t << 6;
    if (tid < 64) {
      int2 v = rc[e0 + tid];
      int r = v.x, c = v.y;
      s_ri[tid] = r;
      float ax = coord[3*r], ay = coord[3*r+1], az = coord[3*r+2];
      float bx = coord[3*c], by = coord[3*c+1], bz = coord[3*c+2];
      float dx = ax-bx, dy = ay-by, dz = az-bz;
      s_cd[tid][0] = dx; s_cd[tid][1] = dy; s_cd[tid][2] = dz;
      s_rad[tid] = dx*dx + dy*dy + dz*dz;
      s_phi[tid] = 0.f;
    }
    { // gather h rows (bf16) into swizzled fragment order
      int2 v = rc[e0 + el];
      const s16x8* hr = (const s16x8*)(hb + (size_t)v.x*128 + q*32);
      const s16x8* hc = (const s16x8*)(hb + (size_t)v.y*128 + q*32);
#pragma unroll
      for (int lg = 0; lg < 4; ++lg) {
        *(s16x8*)sptr(sb0, fi0, lg*16 + er) = hr[lg];
        *(s16x8*)sptr(sb1, fi0, lg*16 + er) = hc[lg];
      }
    }
    __syncthreads();                                            // S1

    // GEMM1: D[f][e] = W1a^T hrow^T + W1b^T hcol^T
    f32x4 acc[2][4] = {};
#pragma unroll
    for (int et = 0; et < 4; ++et)
#pragma unroll
      for (int ks = 0; ks < 4; ++ks) {
        s16x8 br = *(const s16x8*)sptr(sb0, et*4+ks, lane);
        s16x8 bc = *(const s16x8*)sptr(sb1, et*4+ks, lane);
        acc[0][et] = mfma16(wf[0][0][ks], br, acc[0][et]);
        acc[1][et] = mfma16(wf[0][1][ks], br, acc[1][et]);
        acc[0][et] = mfma16(wf[1][0][ks], bc, acc[0][et]);
        acc[1][et] = mfma16(wf[1][1][ks], bc, acc[1][et]);
      }
    __syncthreads();                                            // S2

    // epilogue1: + radial*W1c + be1, SiLU -> t1 frags into sb0
#pragma unroll
    for (int f2 = 0; f2 < 2; ++f2) {
      const int ft = 2*w + f2, f0 = ft*16 + rgrp*4;
      const int ks2 = f0 >> 5, lg2 = (f0 & 31) >> 3, j0 = f0 & 7;
      f32x4 w1c = *(const f32x4*)&s_vec[3][f0];
      f32x4 b1  = *(const f32x4*)&s_vec[0][f0];
#pragma unroll
      for (int et = 0; et < 4; ++et) {
        float rad = s_rad[et*16 + ecol];
        f32x4 x = acc[f2][et];
        x.x = silu_f(x.x + rad*w1c.x + b1.x);
        x.y = silu_f(x.y + rad*w1c.y + b1.y);
        x.z = silu_f(x.z + rad*w1c.z + b1.z);
        x.w = silu_f(x.w + rad*w1c.w + b1.w);
        uint2 p; p.x = pack2(x.x, x.y); p.y = pack2(x.z, x.w);
        *(uint2*)((char*)sptr(sb0, et*4 + ks2, lg2*16 + ecol) + 2*j0) = p;
      }
    }
    __syncthreads();                                            // S3

    // GEMM2: edge_feat
    f32x4 a2[2][4] = {};
#pragma unroll
    for (int et = 0; et < 4; ++et)
#pragma unroll
      for (int ks = 0; ks < 4; ++ks) {
        s16x8 b = *(const s16x8*)sptr(sb0, et*4+ks, lane);
        a2[0][et] = mfma16(wf[2][0][ks], b, a2[0][et]);
        a2[1][et] = mfma16(wf[2][1][ks], b, a2[1][et]);
      }
    // epilogue2: + be2, SiLU; frags into sb1; DPP segmented suffix-sum over
    // the 16-lane edge group (rows sorted => segments contiguous), heads
    // issue the deduplicated global atomics.
#pragma unroll
    for (int et = 0; et < 4; ++et) {
      const int r_l = s_ri[et*16 + ecol];
      f32x4 xx0, xx1;
#pragma unroll
      for (int f2 = 0; f2 < 2; ++f2) {
        const int ft = 2*w + f2, f0 = ft*16 + rgrp*4;
        const int ks2 = f0 >> 5, lg2 = (f0 & 31) >> 3, j0 = f0 & 7;
        f32x4 b2 = *(const f32x4*)&s_vec[1][f0];
        f32x4 x = a2[f2][et];
        x.x = silu_f(x.x + b2.x); x.y = silu_f(x.y + b2.y);
        x.z = silu_f(x.z + b2.z); x.w = silu_f(x.w + b2.w);
        uint2 p; p.x = pack2(x.x, x.y); p.y = pack2(x.z, x.w);
        *(uint2*)((char*)sptr(sb1, et*4 + ks2, lg2*16 + ecol) + 2*j0) = p;
        if (f2 == 0) xx0 = x; else xx1 = x;
      }
#define SEG_ROUND(CTRL) { \
      int rn = dppi<CTRL>(r_l); \
      bool ok = (rn == r_l); \
      float u; \
      u = dppf<CTRL>(xx0.x); xx0.x += ok ? u : 0.f; \
      u = dppf<CTRL>(xx0.y); xx0.y += ok ? u : 0.f; \
      u = dppf<CTRL>(xx0.z); xx0.z += ok ? u : 0.f; \
      u = dppf<CTRL>(xx0.w); xx0.w += ok ? u : 0.f; \
      u = dppf<CTRL>(xx1.x); xx1.x += ok ? u : 0.f; \
      u = dppf<CTRL>(xx1.y); xx1.y += ok ? u : 0.f; \
      u = dppf<CTRL>(xx1.z); xx1.z += ok ? u : 0.f; \
      u = dppf<CTRL>(xx1.w); xx1.w += ok ? u : 0.f; }
      SEG_ROUND(0x101)   // row_shl:1
      SEG_ROUND(0x102)   // row_shl:2
      SEG_ROUND(0x104)   // row_shl:4
      SEG_ROUND(0x108)   // row_shl:8
#undef SEG_ROUND
      const int rprev = dppi<0x111>(r_l);   // row_shr:1, OOB lanes -> -1
      if (rprev != r_l) {
        const int f0a = (2*w+0)*16 + rgrp*4;
        const int f0b = (2*w+1)*16 + rgrp*4;
        float* aga = aggh + (size_t)r_l*128 + f0a;
        float* agb = aggh + (size_t)r_l*128 + f0b;
        atomicAdd(aga+0, xx0.x); atomicAdd(aga+1, xx0.y);
        atomicAdd(aga+2, xx0.z); atomicAdd(aga+3, xx0.w);
        atomicAdd(agb+0, xx1.x); atomicAdd(agb+1, xx1.y);
        atomicAdd(agb+2, xx1.z); atomicAdd(agb+3, xx1.w);
      }
    }
    __syncthreads();                                            // S4

    // GEMM3: phi = silu(ef@Wc1+bc1) @ Wc2
    f32x4 a3[2][4] = {};
#pragma unroll
    for (int et = 0; et < 4; ++et)
#pragma unroll
      for (int ks = 0; ks < 4; ++ks) {
        s16x8 b = *(const s16x8*)sptr(sb1, et*4+ks, lane);
        a3[0][et] = mfma16(wf[3][0][ks], b, a3[0][et]);
        a3[1][et] = mfma16(wf[3][1][ks], b, a3[1][et]);
      }
#pragma unroll
    for (int et = 0; et < 4; ++et) {
      float p = 0.f;
#pragma unroll
      for (int f2 = 0; f2 < 2; ++f2) {
        const int f0 = (2*w+f2)*16 + rgrp*4;
        f32x4 bc = *(const f32x4*)&s_vec[2][f0];
        f32x4 wc = *(const f32x4*)&s_vec[4][f0];
        f32x4 x = a3[f2][et];
        p += silu_f(x.x + bc.x)*wc.x + silu_f(x.y + bc.y)*wc.y
           + silu_f(x.z + bc.z)*wc.z + silu_f(x.w + bc.w)*wc.w;
      }
      p += __shfl_xor(p, 16);
      p += __shfl_xor(p, 32);
      if (rgrp == 0) atomicAdd(&s_phi[et*16 + ecol], p);
    }
    __syncthreads();                                            // S5

    // coord aggregation: segmented suffix-sum over the 64 sorted rows
    if (tid < 64) {
      int r = s_ri[tid];
      float ph = s_phi[tid];
      float cx = s_cd[tid][0]*ph, cy = s_cd[tid][1]*ph, cz = s_cd[tid][2]*ph, c1 = 1.f;
#pragma unroll
      for (int d = 1; d < 64; d <<= 1) {
        const int sl = tid + d;
        int   r2 = __shfl(r,  sl, 64);
        float ux = __shfl(cx, sl, 64), uy = __shfl(cy, sl, 64);
        float uz = __shfl(cz, sl, 64), uw = __shfl(c1, sl, 64);
        if ((sl < 64) && (r2 == r)) { cx+=ux; cy+=uy; cz+=uz; c1+=uw; }
      }
      if (tid == 0 || s_ri[tid-1] != r) {
        atomicAdd(&aggc[3*r+0], cx); atomicAdd(&aggc[3*r+1], cy);
        atomicAdd(&aggc[3*r+2], cz); atomicAdd(&cntb[r], c1);
      }
    }
    __syncthreads();                                            // S6
  }
}

// ---------- node kernel ----------
__global__ __launch_bounds__(256, 2)
void node_kernel(const short* __restrict__ hb, const float* __restrict__ h32,
                 const short* __restrict__ wp, const float* __restrict__ bn1,
                 const float* __restrict__ bn2, float* __restrict__ hout)
{
  __shared__ short sA[2][16][64][8];
  __shared__ float s_vec[2][128];
  __shared__ float s_out[64][132];
  const int tid  = threadIdx.x, w = tid >> 6, lane = tid & 63;
  const int ecol = lane & 15, rgrp = lane >> 4;
  if (tid < 128) { s_vec[0][tid] = bn1[tid]; s_vec[1][tid] = bn2[tid]; }

  s16x8 wf[3][2][4];
#pragma unroll
  for (int m = 0; m < 3; ++m)
#pragma unroll
    for (int f2 = 0; f2 < 2; ++f2)
#pragma unroll
      for (int ks = 0; ks < 4; ++ks)
        wf[m][f2][ks] = *(const s16x8*)(wp + (4+m)*16384 + ((((2*w+f2)<<2) + ks)*64 + lane)*8);

  const int n0 = blockIdx.x << 6;
  const int el = tid >> 2, q = tid & 3;
  const int fi0 = ((el >> 4) << 2) + q, er = el & 15;
  {
    const int node = n0 + el;
    if (node < NN) {
      const s16x8* hr = (const s16x8*)(hb + node*128 + q*32);
      const float* ap = hout + node*128 + q*32;   // agg_h lives in d_out
#pragma unroll
      for (int lg = 0; lg < 4; ++lg) {
        *(s16x8*)&sA[0][fi0][lg*16 + er][0] = hr[lg];
        f32x4 u = *(const f32x4*)(ap + lg*8);
        f32x4 v = *(const f32x4*)(ap + lg*8 + 4);
        uint4 o;
        o.x = pack2(u.x, u.y); o.y = pack2(u.z, u.w);
        o.z = pack2(v.x, v.y); o.w = pack2(v.z, v.w);
        *(uint4*)&sA[1][fi0][lg*16 + er][0] = o;
      }
    } else {
      s16x8 z = {};
#pragma unroll
      for (int lg = 0; lg < 4; ++lg) {
        *(s16x8*)&sA[0][fi0][lg*16 + er][0] = z;
        *(s16x8*)&sA[1][fi0][lg*16 + er][0] = z;
      }
    }
  }
  __syncthreads();

  f32x4 acc[2][4] = {};
#pragma unroll
  for (int et = 0; et < 4; ++et)
#pragma unroll
    for (int ks = 0; ks < 4; ++ks) {
      s16x8 bh = *(const s16x8*)&sA[0][et*4+ks][lane][0];
      s16x8 ba = *(const s16x8*)&sA[1][et*4+ks][lane][0];
      acc[0][et] = mfma16(wf[0][0][ks], bh, acc[0][et]);
      acc[1][et] = mfma16(wf[0][1][ks], bh, acc[1][et]);
      acc[0][et] = mfma16(wf[1][0][ks], ba, acc[0][et]);
      acc[1][et] = mfma16(wf[1][1][ks], ba, acc[1][et]);
    }
  __syncthreads();
#pragma unroll
  for (int f2 = 0; f2 < 2; ++f2) {
    const int ft = 2*w + f2, f0 = ft*16 + rgrp*4;
    const int ks2 = f0 >> 5, lg2 = (f0 & 31) >> 3, j0 = f0 & 7;
    f32x4 b1 = *(const f32x4*)&s_vec[0][f0];
#pragma unroll
    for (int et = 0; et < 4; ++et) {
      f32x4 x = acc[f2][et];
      x.x = silu_f(x.x + b1.x); x.y = silu_f(x.y + b1.y);
      x.z = silu_f(x.z + b1.z); x.w = silu_f(x.w + b1.w);
      uint2 p; p.x = pack2(x.x, x.y); p.y = pack2(x.z, x.w);
      *(uint2*)&sA[0][et*4 + ks2][lg2*16 + ecol][j0] = p;
    }
  }
  __syncthreads();

  f32x4 a2[2][4] = {};
#pragma unroll
  for (int et = 0; et < 4; ++et)
#pragma unroll
    for (int ks = 0; ks < 4; ++ks) {
      s16x8 b = *(const s16x8*)&sA[0][et*4+ks][lane][0];
      a2[0][et] = mfma16(wf[2][0][ks], b, a2[0][et]);
      a2[1][et] = mfma16(wf[2][1][ks], b, a2[1][et]);
    }
#pragma unroll
  for (int f2 = 0; f2 < 2; ++f2) {
    const int f0 = (2*w+f2)*16 + rgrp*4;
    f32x4 b2 = *(const f32x4*)&s_vec[1][f0];
#pragma unroll
    for (int et = 0; et < 4; ++et) {
      f32x4 x = a2[f2][et];
      x.x += b2.x; x.y += b2.y; x.z += b2.z; x.w += b2.w;
      *(f32x4*)&s_out[et*16 + ecol][f0] = x;
    }
  }
  __syncthreads();
  {
    const int node = n0 + el;
    if (node < NN) {
#pragma unroll
      for (int i = 0; i < 8; ++i) {
        f32x4 o  = *(const f32x4*)&s_out[el][q*32 + i*4];
        f32x4 hv = *(const f32x4*)(h32 + node*128 + q*32 + i*4);
        o.x += hv.x; o.y += hv.y; o.z += hv.z; o.w += hv.w;
        *(f32x4*)(hout + node*128 + q*32 + i*4) = o;
      }
    }
  }
}

// ---------- coord kernel ----------
__global__ void coord_kernel(const float* __restrict__ coord, const float* __restrict__ aggc,
                             const float* __restrict__ cntb, float* __restrict__ out)
{
  int i = blockIdx.x*256 + threadIdx.x;
  if (i < NN) {
    float inv = __builtin_amdgcn_rcpf(fmaxf(cntb[i], 1.f));
    out[NHF + 3*i+0] = coord[3*i+0] + aggc[3*i+0]*inv;
    out[NHF + 3*i+1] = coord[3*i+1] + aggc[3*i+1]*inv;
    out[NHF + 3*i+2] = coord[3*i+2] + aggc[3*i+2]*inv;
  }
}

extern "C" void kernel_launch(void* const* d_in, const int* in_sizes, int n_in,
                              void* d_out, int out_size, void* d_ws, size_t ws_size,
                              hipStream_t stream)
{
  (void)in_sizes; (void)n_in; (void)out_size; (void)ws_size;
  const float* h    = (const float*)d_in[0];
  const float* crd  = (const float*)d_in[1];
  const int*   eidx = (const int*)  d_in[2];
  const float* We1  = (const float*)d_in[3];
  const float* be1  = (const float*)d_in[4];
  const float* We2  = (const float*)d_in[5];
  const float* be2  = (const float*)d_in[6];
  const float* Wn1  = (const float*)d_in[7];
  const float* bn1  = (const float*)d_in[8];
  const float* Wn2  = (const float*)d_in[9];
  const float* bn2  = (const float*)d_in[10];
  const float* Wc1  = (const float*)d_in[11];
  const float* bc1  = (const float*)d_in[12];
  const float* Wc2  = (const float*)d_in[13];
  float* out = (float*)d_out;
  char*  ws  = (char*)d_ws;

  short* hb   = (short*)ws;                    // 12,800,000 B
  short* wp   = (short*)(ws + 12800000);       //    229,376 B
  float* aggc = (float*)(ws + 13029376);       //    600,000 B
  float* cntb = (float*)(ws + 13629376);       //    200,000 B
  int*   hist = (int*)  (ws + 13829376);       //    200,000 B
  int*   cur  = (int*)  (ws + 14029376);       //    200,000 B
  int2*  rc   = (int2*) (ws + 14229376);       // 12,800,000 B  (end: 27,029,376)

  // zero accumulators every call (harness does not re-poison between replays)
  hipMemsetAsync(out, 0, (size_t)NHF*4, stream);          // agg_h region of d_out
  hipMemsetAsync(ws + 13029376, 0, 800000, stream);       // agg_c + cnt
  hipMemsetAsync(ws + 13829376, 0, 200000, stream);       // hist

  pack_weights<<<dim3(224), dim3(64), 0, stream>>>(We1, We2, Wc1, Wn1, Wn2, wp);
  hconv<<<dim3(3125), dim3(256), 0, stream>>>(h, hb);
  hist_k<<<dim3(6250), dim3(256), 0, stream>>>(eidx, hist);
  scan_k<<<dim3(1), dim3(256), 0, stream>>>(hist, cur);
  scatter_k<<<dim3(6250), dim3(256), 0, stream>>>(eidx, cur, rc);
  edge_kernel<<<dim3(2048), dim3(256), 0, stream>>>(hb, crd, rc, wp,
                                                    be1, be2, bc1, We1, Wc2,
                                                    out, aggc, cntb);
  node_kernel<<<dim3(782), dim3(256), 0, stream>>>(hb, h, wp, bn1, bn2, out);
  coord_kernel<<<dim3(196), dim3(256), 0, stream>>>(crd, aggc, cntb, out);
}

// Round 5
// 783.508 us; speedup vs baseline: 1.5366x; 1.0651x over previous
//
#include <hip/hip_runtime.h>

// EGNN E_GCL fused kernels for MI355X (gfx950), bf16 MFMA path.
// Round 5: hoist all h-side GEMMs out of the edge/node kernels:
//   A1[n][384] = h @ [We1a | We1b | Wn1a]  (one dense pre-GEMM, L3-resident)
// Edge kernel: t1 = silu(A1r[row] + A1c[col] + rad*W1c + be1) built from
// register gathers (GEMM1 deleted: -64 MFMA, -160KB LDS traffic per tile).
// Node kernel: t = silu(A1n[n] + agg_h@Wn1b + bn1). Frees 64 weight VGPRs ->
// __launch_bounds__(256,3). Keeps R4's DPP scan, LDS swizzle, silu-rcp, cvt_pk.

typedef float f32x4 __attribute__((ext_vector_type(4)));
typedef short s16x8 __attribute__((ext_vector_type(8)));

#define NN   50000
#define EE   1600000
#define NHF  6400000   // N*128
#define NBIN 50000
#define NT   25000     // 64-edge tiles

__device__ __forceinline__ unsigned short f2bf(float x){
  union { float f; unsigned int u; } v; v.f = x;
  unsigned int r = v.u + 0x7fffu + ((v.u >> 16) & 1u);
  return (unsigned short)(r >> 16);
}
__device__ __forceinline__ unsigned int pack2(float a, float b){
  unsigned int r;
  asm("v_cvt_pk_bf16_f32 %0, %1, %2" : "=v"(r) : "v"(a), "v"(b));
  return r;
}
__device__ __forceinline__ float silu_f(float x){
  return x * __builtin_amdgcn_rcpf(1.f + __expf(-x));
}
__device__ __forceinline__ float bflo(unsigned int u){ return __uint_as_float(u << 16); }
__device__ __forceinline__ float bfhi(unsigned int u){ return __uint_as_float(u & 0xffff0000u); }

__device__ __forceinline__ f32x4 mfma16(s16x8 a, s16x8 b, f32x4 c){
  return __builtin_amdgcn_mfma_f32_16x16x32_bf16(a, b, c, 0, 0, 0);
}

template<int CTRL> __device__ __forceinline__ float dppf(float x){
  return __int_as_float(__builtin_amdgcn_update_dpp(0, __float_as_int(x), CTRL, 0xF, 0xF, true));
}
template<int CTRL> __device__ __forceinline__ int dppi(int x){
  return __builtin_amdgcn_update_dpp(-1, x, CTRL, 0xF, 0xF, false);
}

__device__ __forceinline__ short* sptr(short* base, int fi, int slot){
  return (short*)((char*)base + (fi << 10) + (((slot << 4) ^ ((fi & 3) << 5))));
}

// ---------- weight pack: A-fragments of W^T ----------
// 0=We1a 1=We1b 2=We2 3=Wc1 4=Wn1a 5=Wn1b 6=Wn2
__global__ void pack_weights(const float* __restrict__ We1, const float* __restrict__ We2,
                             const float* __restrict__ Wc1, const float* __restrict__ Wn1,
                             const float* __restrict__ Wn2, short* __restrict__ wp)
{
  int b = blockIdx.x;              // 7*32 blocks, 64 threads
  int m = b >> 5, t = b & 31;
  int ft = t >> 2, ks = t & 3;
  int lane = threadIdx.x;
  const float* src;
  switch (m) {
    case 0: src = We1;            break;
    case 1: src = We1 + 128*128;  break;
    case 2: src = We2;            break;
    case 3: src = Wc1;            break;
    case 4: src = Wn1;            break;
    case 5: src = Wn1 + 128*128;  break;
    default: src = Wn2;           break;
  }
  short* dst = wp + m*16384 + (((ft<<2) + ks)*64 + lane)*8;
  int f  = (ft<<4) + (lane & 15);
  int kb = (ks<<5) + ((lane >> 4) << 3);
#pragma unroll
  for (int j = 0; j < 8; ++j)
    dst[j] = (short)f2bf(src[(kb + j)*128 + f]);
}

// ---------- pre-GEMM: A1[n][384] = h @ [We1a | We1b | Wn1a] ----------
__global__ __launch_bounds__(256, 2)
void a1_kernel(const float* __restrict__ h32, const short* __restrict__ wp,
               unsigned short* __restrict__ A1)
{
  __shared__ short sA[16][64][8];
  const int tid = threadIdx.x, w = tid >> 6, lane = tid & 63;
  const int n0 = blockIdx.x << 6;
  const int el = tid >> 2, q = tid & 3;
  const int fi0 = ((el >> 4) << 2) + q, er = el & 15;
  {
    const int node = n0 + el;
    if (node < NN) {
      const float* hp = h32 + (size_t)node*128 + q*32;
#pragma unroll
      for (int lg = 0; lg < 4; ++lg) {
        f32x4 u = *(const f32x4*)(hp + lg*8);
        f32x4 v = *(const f32x4*)(hp + lg*8 + 4);
        uint4 o;
        o.x = pack2(u.x, u.y); o.y = pack2(u.z, u.w);
        o.z = pack2(v.x, v.y); o.w = pack2(v.z, v.w);
        *(uint4*)&sA[fi0][lg*16 + er][0] = o;
      }
    } else {
      s16x8 z = {};
#pragma unroll
      for (int lg = 0; lg < 4; ++lg) *(s16x8*)&sA[fi0][lg*16 + er][0] = z;
    }
  }
  __syncthreads();

  static const int wpm[3] = {0, 1, 4};
#pragma unroll
  for (int p = 0; p < 2; ++p) {
    s16x8 af[3][4];
#pragma unroll
    for (int j = 0; j < 3; ++j) {
      const int ftg = w*6 + p*3 + j;
      const int mi = ftg >> 3, fti = ftg & 7;
#pragma unroll
      for (int ks = 0; ks < 4; ++ks)
        af[j][ks] = *(const s16x8*)(wp + wpm[mi]*16384 + (((fti<<2) + ks)*64 + lane)*8);
    }
    f32x4 acc[3][4] = {};
#pragma unroll
    for (int et = 0; et < 4; ++et)
#pragma unroll
      for (int ks = 0; ks < 4; ++ks) {
        s16x8 b = *(const s16x8*)&sA[et*4+ks][lane][0];
#pragma unroll
        for (int j = 0; j < 3; ++j)
          acc[j][et] = mfma16(af[j][ks], b, acc[j][et]);
      }
#pragma unroll
    for (int j = 0; j < 3; ++j) {
      const int ftg = w*6 + p*3 + j;
#pragma unroll
      for (int et = 0; et < 4; ++et) {
        const int node = n0 + et*16 + (lane & 15);
        if (node < NN) {
          f32x4 a = acc[j][et];
          uint2 o; o.x = pack2(a.x, a.y); o.y = pack2(a.z, a.w);
          *(uint2*)(A1 + (size_t)node*384 + ftg*16 + ((lane >> 4) << 2)) = o;
        }
      }
    }
  }
}

// ---------- counting sort by row ----------
__global__ void hist_k(const int* __restrict__ eidx, int* __restrict__ hist)
{
  int e = blockIdx.x*256 + threadIdx.x;
  if (e < EE) atomicAdd(&hist[eidx[e]], 1);
}

__global__ void scan_k(const int* __restrict__ hist, int* __restrict__ cur)
{
  __shared__ int s_a[256];
  const int t = threadIdx.x;
  const int lo = t * 196;
  const int hi = (lo + 196 < NBIN) ? lo + 196 : NBIN;
  int s = 0;
  for (int i = lo; i < hi; ++i) s += hist[i];
  s_a[t] = s;
  __syncthreads();
  int acc = s;
#pragma unroll
  for (int d = 1; d < 256; d <<= 1) {
    int u = (t >= d) ? s_a[t - d] : 0;
    __syncthreads();
    acc += u;
    s_a[t] = acc;
    __syncthreads();
  }
  int run = acc - s;
  for (int i = lo; i < hi; ++i) { cur[i] = run; run += hist[i]; }
}

__global__ void scatter_k(const int* __restrict__ eidx, int* __restrict__ cur,
                          int* __restrict__ perm)
{
  int e = blockIdx.x*256 + threadIdx.x;
  if (e < EE) {
    int p = atomicAdd(&cur[eidx[e]], 1);
    perm[p] = e;
  }
}

// ---------- edge kernel ----------
__global__ __launch_bounds__(256, 3)
void edge_kernel(const unsigned short* __restrict__ A1, const float* __restrict__ coord,
                 const int* __restrict__ eidx, const int* __restrict__ perm,
                 const short* __restrict__ wp,
                 const float* __restrict__ be1, const float* __restrict__ be2,
                 const float* __restrict__ bc1, const float* __restrict__ We1,
                 const float* __restrict__ Wc2,
                 float* __restrict__ aggh, float* __restrict__ aggc,
                 float* __restrict__ cntb)
{
  __shared__ short sAf[2][16*64*8];      // 32 KiB swizzled frag tiles: t1 / ef
  __shared__ float s_vec[5][128];        // be1, be2, bc1, W1c, Wc2
  __shared__ float s_rad[64];
  __shared__ float s_cd[64][3];
  __shared__ int   s_ri[64];
  __shared__ int   s_ci[64];
  __shared__ float s_phi[64];

  const int tid  = threadIdx.x;
  const int w    = tid >> 6, lane = tid & 63;
  const int ecol = lane & 15, rgrp = lane >> 4;

  if (tid < 128) {
    s_vec[0][tid] = be1[tid];
    s_vec[1][tid] = be2[tid];
    s_vec[2][tid] = bc1[tid];
    s_vec[3][tid] = We1[256*128 + tid];
    s_vec[4][tid] = Wc2[tid];
  }

  // persistent weights: We2 + Wc1 = 64 VGPR
  s16x8 wf2[2][4], wf3[2][4];
#pragma unroll
  for (int f2 = 0; f2 < 2; ++f2)
#pragma unroll
    for (int ks = 0; ks < 4; ++ks) {
      wf2[f2][ks] = *(const s16x8*)(wp + 2*16384 + ((((2*w+f2)<<2) + ks)*64 + lane)*8);
      wf3[f2][ks] = *(const s16x8*)(wp + 3*16384 + ((((2*w+f2)<<2) + ks)*64 + lane)*8);
    }

  short* sb0 = &sAf[0][0];
  short* sb1 = &sAf[1][0];

  // contiguous tile chunk per block (row-sorted => L1/L2 locality for A1r)
  const int tbeg = blockIdx.x * 13;
  const int tend = (tbeg + 13 < NT) ? tbeg + 13 : NT;

  for (int t = tbeg; t < tend; ++t) {
    const int e0 = t << 6;
    if (tid < 64) {
      int e = perm[e0 + tid];
      int r = eidx[e], c = eidx[EE + e];
      s_ri[tid] = r; s_ci[tid] = c;
      float ax = coord[3*r], ay = coord[3*r+1], az = coord[3*r+2];
      float bx = coord[3*c], by = coord[3*c+1], bz = coord[3*c+2];
      float dx = ax-bx, dy = ay-by, dz = az-bz;
      s_cd[tid][0] = dx; s_cd[tid][1] = dy; s_cd[tid][2] = dz;
      s_rad[tid] = dx*dx + dy*dy + dz*dz;
      s_phi[tid] = 0.f;
    }
    __syncthreads();                                            // S0

    // ep0: t1 = silu(A1r[row] + A1c[col] + rad*W1c + be1) -> frags into sb0
    {
      int rr[4], cc[4]; float rd[4];
#pragma unroll
      for (int et = 0; et < 4; ++et) {
        const int e_ = et*16 + ecol;
        rr[et] = s_ri[e_]; cc[et] = s_ci[e_]; rd[et] = s_rad[e_];
      }
      uint2 gr[2][4], gc[2][4];
#pragma unroll
      for (int f2 = 0; f2 < 2; ++f2) {
        const int f0 = (2*w+f2)*16 + (rgrp << 2);
#pragma unroll
        for (int et = 0; et < 4; ++et) {
          gr[f2][et] = *(const uint2*)(A1 + (size_t)rr[et]*384 + f0);
          gc[f2][et] = *(const uint2*)(A1 + (size_t)cc[et]*384 + 128 + f0);
        }
      }
#pragma unroll
      for (int f2 = 0; f2 < 2; ++f2) {
        const int f0 = (2*w+f2)*16 + (rgrp << 2);
        const int ks2 = f0 >> 5, lg2 = (f0 & 31) >> 3, j0 = f0 & 7;
        f32x4 w1c = *(const f32x4*)&s_vec[3][f0];
        f32x4 b1  = *(const f32x4*)&s_vec[0][f0];
#pragma unroll
        for (int et = 0; et < 4; ++et) {
          const uint2 r2v = gr[f2][et], c2v = gc[f2][et];
          f32x4 x;
          x.x = silu_f(bflo(r2v.x) + bflo(c2v.x) + rd[et]*w1c.x + b1.x);
          x.y = silu_f(bfhi(r2v.x) + bfhi(c2v.x) + rd[et]*w1c.y + b1.y);
          x.z = silu_f(bflo(r2v.y) + bflo(c2v.y) + rd[et]*w1c.z + b1.z);
          x.w = silu_f(bfhi(r2v.y) + bfhi(c2v.y) + rd[et]*w1c.w + b1.w);
          uint2 p; p.x = pack2(x.x, x.y); p.y = pack2(x.z, x.w);
          *(uint2*)((char*)sptr(sb0, et*4 + ks2, lg2*16 + ecol) + 2*j0) = p;
        }
      }
    }
    __syncthreads();                                            // S1

    // GEMM2: ef = silu(t1 @ We2 + be2)
    f32x4 a2[2][4] = {};
#pragma unroll
    for (int et = 0; et < 4; ++et)
#pragma unroll
      for (int ks = 0; ks < 4; ++ks) {
        s16x8 b = *(const s16x8*)sptr(sb0, et*4+ks, lane);
        a2[0][et] = mfma16(wf2[0][ks], b, a2[0][et]);
        a2[1][et] = mfma16(wf2[1][ks], b, a2[1][et]);
      }
    // ep2: SiLU; frags into sb1; DPP segmented suffix-sum dedup -> agg_h atomics
#pragma unroll
    for (int et = 0; et < 4; ++et) {
      const int r_l = s_ri[et*16 + ecol];
      f32x4 xx0, xx1;
#pragma unroll
      for (int f2 = 0; f2 < 2; ++f2) {
        const int f0 = (2*w+f2)*16 + (rgrp << 2);
        const int ks2 = f0 >> 5, lg2 = (f0 & 31) >> 3, j0 = f0 & 7;
        f32x4 b2 = *(const f32x4*)&s_vec[1][f0];
        f32x4 x = a2[f2][et];
        x.x = silu_f(x.x + b2.x); x.y = silu_f(x.y + b2.y);
        x.z = silu_f(x.z + b2.z); x.w = silu_f(x.w + b2.w);
        uint2 p; p.x = pack2(x.x, x.y); p.y = pack2(x.z, x.w);
        *(uint2*)((char*)sptr(sb1, et*4 + ks2, lg2*16 + ecol) + 2*j0) = p;
        if (f2 == 0) xx0 = x; else xx1 = x;
      }
#define SEG_ROUND(CTRL) { \
      int rn = dppi<CTRL>(r_l); \
      bool ok = (rn == r_l); \
      float u; \
      u = dppf<CTRL>(xx0.x); xx0.x += ok ? u : 0.f; \
      u = dppf<CTRL>(xx0.y); xx0.y += ok ? u : 0.f; \
      u = dppf<CTRL>(xx0.z); xx0.z += ok ? u : 0.f; \
      u = dppf<CTRL>(xx0.w); xx0.w += ok ? u : 0.f; \
      u = dppf<CTRL>(xx1.x); xx1.x += ok ? u : 0.f; \
      u = dppf<CTRL>(xx1.y); xx1.y += ok ? u : 0.f; \
      u = dppf<CTRL>(xx1.z); xx1.z += ok ? u : 0.f; \
      u = dppf<CTRL>(xx1.w); xx1.w += ok ? u : 0.f; }
      SEG_ROUND(0x101)
      SEG_ROUND(0x102)
      SEG_ROUND(0x104)
      SEG_ROUND(0x108)
#undef SEG_ROUND
      const int rprev = dppi<0x111>(r_l);
      if (rprev != r_l) {
        const int f0a = (2*w+0)*16 + (rgrp << 2);
        const int f0b = (2*w+1)*16 + (rgrp << 2);
        float* aga = aggh + (size_t)r_l*128 + f0a;
        float* agb = aggh + (size_t)r_l*128 + f0b;
        atomicAdd(aga+0, xx0.x); atomicAdd(aga+1, xx0.y);
        atomicAdd(aga+2, xx0.z); atomicAdd(aga+3, xx0.w);
        atomicAdd(agb+0, xx1.x); atomicAdd(agb+1, xx1.y);
        atomicAdd(agb+2, xx1.z); atomicAdd(agb+3, xx1.w);
      }
    }
    __syncthreads();                                            // S2

    // GEMM3: phi = silu(ef@Wc1+bc1) @ Wc2
    f32x4 a3[2][4] = {};
#pragma unroll
    for (int et = 0; et < 4; ++et)
#pragma unroll
      for (int ks = 0; ks < 4; ++ks) {
        s16x8 b = *(const s16x8*)sptr(sb1, et*4+ks, lane);
        a3[0][et] = mfma16(wf3[0][ks], b, a3[0][et]);
        a3[1][et] = mfma16(wf3[1][ks], b, a3[1][et]);
      }
#pragma unroll
    for (int et = 0; et < 4; ++et) {
      float p = 0.f;
#pragma unroll
      for (int f2 = 0; f2 < 2; ++f2) {
        const int f0 = (2*w+f2)*16 + (rgrp << 2);
        f32x4 bc = *(const f32x4*)&s_vec[2][f0];
        f32x4 wc = *(const f32x4*)&s_vec[4][f0];
        f32x4 x = a3[f2][et];
        p += silu_f(x.x + bc.x)*wc.x + silu_f(x.y + bc.y)*wc.y
           + silu_f(x.z + bc.z)*wc.z + silu_f(x.w + bc.w)*wc.w;
      }
      p += __shfl_xor(p, 16);
      p += __shfl_xor(p, 32);
      if (rgrp == 0) atomicAdd(&s_phi[et*16 + ecol], p);
    }
    __syncthreads();                                            // S3

    // coord aggregation: segmented suffix-sum over the 64 sorted rows
    if (tid < 64) {
      int r = s_ri[tid];
      float ph = s_phi[tid];
      float cx = s_cd[tid][0]*ph, cy = s_cd[tid][1]*ph, cz = s_cd[tid][2]*ph, c1 = 1.f;
#pragma unroll
      for (int d = 1; d < 64; d <<= 1) {
        const int sl = tid + d;
        int   r2 = __shfl(r,  sl, 64);
        float ux = __shfl(cx, sl, 64), uy = __shfl(cy, sl, 64);
        float uz = __shfl(cz, sl, 64), uw = __shfl(c1, sl, 64);
        if ((sl < 64) && (r2 == r)) { cx+=ux; cy+=uy; cz+=uz; c1+=uw; }
      }
      if (tid == 0 || s_ri[tid-1] != r) {
        atomicAdd(&aggc[3*r+0], cx); atomicAdd(&aggc[3*r+1], cy);
        atomicAdd(&aggc[3*r+2], cz); atomicAdd(&cntb[r], c1);
      }
    }
    __syncthreads();                                            // S4
  }
}

// ---------- node kernel: h_out = h + silu(A1n + agg_h@Wn1b + bn1) @ Wn2 + bn2
__global__ __launch_bounds__(256, 2)
void node_kernel(const unsigned short* __restrict__ A1, const float* __restrict__ h32,
                 const short* __restrict__ wp, const float* __restrict__ bn1,
                 const float* __restrict__ bn2, float* __restrict__ hout)
{
  __shared__ short sA[16][64][8];
  __shared__ float s_vec[2][128];
  const int tid  = threadIdx.x, w = tid >> 6, lane = tid & 63;
  const int ecol = lane & 15, rgrp = lane >> 4;
  if (tid < 128) { s_vec[0][tid] = bn1[tid]; s_vec[1][tid] = bn2[tid]; }

  s16x8 wfa[2][4], wfb[2][4];          // Wn1b, Wn2
#pragma unroll
  for (int f2 = 0; f2 < 2; ++f2)
#pragma unroll
    for (int ks = 0; ks < 4; ++ks) {
      wfa[f2][ks] = *(const s16x8*)(wp + 5*16384 + ((((2*w+f2)<<2) + ks)*64 + lane)*8);
      wfb[f2][ks] = *(const s16x8*)(wp + 6*16384 + ((((2*w+f2)<<2) + ks)*64 + lane)*8);
    }

  const int n0 = blockIdx.x << 6;
  const int el = tid >> 2, q = tid & 3;
  const int fi0 = ((el >> 4) << 2) + q, er = el & 15;
  { // stage agg_h (lives in d_out h region) as bf16 frags
    const int node = n0 + el;
    if (node < NN) {
      const float* ap = hout + (size_t)node*128 + q*32;
#pragma unroll
      for (int lg = 0; lg < 4; ++lg) {
        f32x4 u = *(const f32x4*)(ap + lg*8);
        f32x4 v = *(const f32x4*)(ap + lg*8 + 4);
        uint4 o;
        o.x = pack2(u.x, u.y); o.y = pack2(u.z, u.w);
        o.z = pack2(v.x, v.y); o.w = pack2(v.z, v.w);
        *(uint4*)&sA[fi0][lg*16 + er][0] = o;
      }
    } else {
      s16x8 z = {};
#pragma unroll
      for (int lg = 0; lg < 4; ++lg) *(s16x8*)&sA[fi0][lg*16 + er][0] = z;
    }
  }
  __syncthreads();

  f32x4 acc[2][4] = {};
#pragma unroll
  for (int et = 0; et < 4; ++et)
#pragma unroll
    for (int ks = 0; ks < 4; ++ks) {
      s16x8 ba = *(const s16x8*)&sA[et*4+ks][lane][0];
      acc[0][et] = mfma16(wfa[0][ks], ba, acc[0][et]);
      acc[1][et] = mfma16(wfa[1][ks], ba, acc[1][et]);
    }
  __syncthreads();   // all reads of sA done; safe to overwrite with t frags

  // ep: t = silu(acc + A1n[node] + bn1) -> frags back into sA
#pragma unroll
  for (int f2 = 0; f2 < 2; ++f2) {
    const int ft = 2*w + f2, f0 = ft*16 + (rgrp << 2);
    const int ks2 = f0 >> 5, lg2 = (f0 & 31) >> 3, j0 = f0 & 7;
    f32x4 b1 = *(const f32x4*)&s_vec[0][f0];
#pragma unroll
    for (int et = 0; et < 4; ++et) {
      const int node = n0 + et*16 + ecol;
      uint2 g = {0u, 0u};
      if (node < NN) g = *(const uint2*)(A1 + (size_t)node*384 + 256 + f0);
      f32x4 x = acc[f2][et];
      x.x = silu_f(x.x + bflo(g.x) + b1.x);
      x.y = silu_f(x.y + bfhi(g.x) + b1.y);
      x.z = silu_f(x.z + bflo(g.y) + b1.z);
      x.w = silu_f(x.w + bfhi(g.y) + b1.w);
      uint2 p; p.x = pack2(x.x, x.y); p.y = pack2(x.z, x.w);
      *(uint2*)&sA[et*4 + ks2][lg2*16 + ecol][j0] = p;
    }
  }
  __syncthreads();

  f32x4 a2[2][4] = {};
#pragma unroll
  for (int et = 0; et < 4; ++et)
#pragma unroll
    for (int ks = 0; ks < 4; ++ks) {
      s16x8 b = *(const s16x8*)&sA[et*4+ks][lane][0];
      a2[0][et] = mfma16(wfb[0][ks], b, a2[0][et]);
      a2[1][et] = mfma16(wfb[1][ks], b, a2[1][et]);
    }
  // h_out = h + a2 + bn2, written directly (16B per lane)
#pragma unroll
  for (int f2 = 0; f2 < 2; ++f2) {
    const int f0 = (2*w+f2)*16 + (rgrp << 2);
    f32x4 b2 = *(const f32x4*)&s_vec[1][f0];
#pragma unroll
    for (int et = 0; et < 4; ++et) {
      const int node = n0 + et*16 + ecol;
      if (node < NN) {
        f32x4 hv = *(const f32x4*)(h32 + (size_t)node*128 + f0);
        f32x4 x = a2[f2][et];
        x.x += b2.x + hv.x; x.y += b2.y + hv.y;
        x.z += b2.z + hv.z; x.w += b2.w + hv.w;
        *(f32x4*)(hout + (size_t)node*128 + f0) = x;
      }
    }
  }
}

// ---------- coord kernel ----------
__global__ void coord_kernel(const float* __restrict__ coord, const float* __restrict__ aggc,
                             const float* __restrict__ cntb, float* __restrict__ out)
{
  int i = blockIdx.x*256 + threadIdx.x;
  if (i < NN) {
    float inv = __builtin_amdgcn_rcpf(fmaxf(cntb[i], 1.f));
    out[NHF + 3*i+0] = coord[3*i+0] + aggc[3*i+0]*inv;
    out[NHF + 3*i+1] = coord[3*i+1] + aggc[3*i+1]*inv;
    out[NHF + 3*i+2] = coord[3*i+2] + aggc[3*i+2]*inv;
  }
}

extern "C" void kernel_launch(void* const* d_in, const int* in_sizes, int n_in,
                              void* d_out, int out_size, void* d_ws, size_t ws_size,
                              hipStream_t stream)
{
  (void)in_sizes; (void)n_in; (void)out_size; (void)ws_size;
  const float* h    = (const float*)d_in[0];
  const float* crd  = (const float*)d_in[1];
  const int*   eidx = (const int*)  d_in[2];
  const float* We1  = (const float*)d_in[3];
  const float* be1  = (const float*)d_in[4];
  const float* We2  = (const float*)d_in[5];
  const float* be2  = (const float*)d_in[6];
  const float* Wn1  = (const float*)d_in[7];
  const float* bn1  = (const float*)d_in[8];
  const float* Wn2  = (const float*)d_in[9];
  const float* bn2  = (const float*)d_in[10];
  const float* Wc1  = (const float*)d_in[11];
  const float* bc1  = (const float*)d_in[12];
  const float* Wc2  = (const float*)d_in[13];
  float* out = (float*)d_out;
  char*  ws  = (char*)d_ws;

  short*          wp   = (short*)ws;                       //    229,376 B
  unsigned short* A1   = (unsigned short*)(ws + 229376);   // 38,400,000 B
  float*          aggc = (float*)(ws + 38629376);          //    600,000 B
  float*          cntb = (float*)(ws + 39229376);          //    200,000 B
  int*            hist = (int*)  (ws + 39429376);          //    200,000 B
  int*            cur  = (int*)  (ws + 39629376);          //    200,000 B
  int*            perm = (int*)  (ws + 39829376);          //  6,400,000 B (end 46,229,376)

  // zero accumulators every call (harness does not re-poison between replays)
  hipMemsetAsync(out, 0, (size_t)NHF*4, stream);           // agg_h region of d_out
  hipMemsetAsync(ws + 38629376, 0, 800000, stream);        // agg_c + cnt
  hipMemsetAsync(ws + 39429376, 0, 200000, stream);        // hist

  pack_weights<<<dim3(224), dim3(64), 0, stream>>>(We1, We2, Wc1, Wn1, Wn2, wp);
  a1_kernel<<<dim3(782), dim3(256), 0, stream>>>(h, wp, A1);
  hist_k<<<dim3(6250), dim3(256), 0, stream>>>(eidx, hist);
  scan_k<<<dim3(1), dim3(256), 0, stream>>>(hist, cur);
  scatter_k<<<dim3(6250), dim3(256), 0, stream>>>(eidx, cur, perm);
  edge_kernel<<<dim3(1924), dim3(256), 0, stream>>>(A1, crd, eidx, perm, wp,
                                                    be1, be2, bc1, We1, Wc2,
                                                    out, aggc, cntb);
  node_kernel<<<dim3(782), dim3(256), 0, stream>>>(A1, h, wp, bn1, bn2, out);
  coord_kernel<<<dim3(196), dim3(256), 0, stream>>>(crd, aggc, cntb, out);
}